// Round 1
// baseline (3116.421 us; speedup 1.0000x reference)
//
#include <hip/hip_runtime.h>
#include <hip/hip_bf16.h>
#include <math.h>

#define T_TOK 8192
#define DM    1024
#define DFF   4096
#define NE    8
#define DH    512
#define NSLOT (T_TOK*2)

typedef float  f32x4  __attribute__((ext_vector_type(4)));
typedef __bf16 bf16x8 __attribute__((ext_vector_type(8)));

__device__ inline ushort f2bf(float f) {
  union { float f; unsigned int u; } v; v.f = f;
  unsigned int r = (v.u + 0x7FFFu + ((v.u >> 16) & 1u)) >> 16;
  return (ushort)r;
}

__device__ inline void gl_lds16(const void* g, void* l) {
  __builtin_amdgcn_global_load_lds(
      (const __attribute__((address_space(1))) unsigned int*)g,
      (__attribute__((address_space(3))) unsigned int*)l, 16, 0, 0);
}

// ---------------- init / utility ----------------
__global__ void k_init(int* counts, int* fill, float* psum) {
  int i = threadIdx.x;
  if (i < NE) { counts[i] = 0; fill[i] = 0; psum[i] = 0.f; }
}

__global__ void k_zero4(float* p, int n4) {
  int i = blockIdx.x * blockDim.x + threadIdx.x;
  int st = gridDim.x * blockDim.x;
  float4 z = make_float4(0.f, 0.f, 0.f, 0.f);
  for (; i < n4; i += st) ((float4*)p)[i] = z;
}

__global__ void k_cvt_x(const float* __restrict__ x, ushort* __restrict__ xb, int n4) {
  int i = blockIdx.x * blockDim.x + threadIdx.x;
  int st = gridDim.x * blockDim.x;
  for (; i < n4; i += st) {
    float4 v = ((const float4*)x)[i];
    ushort4 o;
    o.x = f2bf(v.x); o.y = f2bf(v.y); o.z = f2bf(v.z); o.w = f2bf(v.w);
    ((ushort4*)xb)[i] = o;
  }
}

// transpose f32 [R][C] -> bf16 [C][R], one expert per blockIdx.z
__global__ __launch_bounds__(256) void k_tr(const float* __restrict__ in,
                                            ushort* __restrict__ out, int R, int C) {
  __shared__ float tile[64][65];
  int e = blockIdx.z;
  in  += (size_t)e * R * C;
  out += (size_t)e * R * C;
  int r0 = blockIdx.y * 64, c0 = blockIdx.x * 64;
  int tx = threadIdx.x & 63, ty = threadIdx.x >> 6;
  for (int i = 0; i < 16; i++) {
    int r = ty + i * 4;
    tile[r][tx] = in[(size_t)(r0 + r) * C + c0 + tx];
  }
  __syncthreads();
  for (int i = 0; i < 16; i++) {
    int c = ty + i * 4;
    out[(size_t)(c0 + c) * R + r0 + tx] = f2bf(tile[tx][c]);
  }
}

// ---------------- gating (fp32) ----------------
// g1 = relu(x @ gw1 + gb1)   [8192 x 512], K=1024
__global__ __launch_bounds__(256) void k_gate1(const float* __restrict__ x,
                                               const float* __restrict__ w,
                                               const float* __restrict__ b,
                                               float* __restrict__ g1) {
  __shared__ float As[64][17];
  __shared__ float Bs[16][65];
  int m0 = blockIdx.y * 64, n0 = blockIdx.x * 64;
  int t = threadIdx.x;
  int tx = t & 15, ty = t >> 4;
  float acc[4][4] = {};
  for (int k0 = 0; k0 < DM; k0 += 16) {
    {
      int r = t >> 2, c4 = (t & 3) * 4;
      float4 v = *(const float4*)&x[(size_t)(m0 + r) * DM + k0 + c4];
      As[r][c4 + 0] = v.x; As[r][c4 + 1] = v.y; As[r][c4 + 2] = v.z; As[r][c4 + 3] = v.w;
    }
    {
      int r = t >> 4, c4 = (t & 15) * 4;
      float4 v = *(const float4*)&w[(size_t)(k0 + r) * DH + n0 + c4];
      Bs[r][c4 + 0] = v.x; Bs[r][c4 + 1] = v.y; Bs[r][c4 + 2] = v.z; Bs[r][c4 + 3] = v.w;
    }
    __syncthreads();
    for (int k = 0; k < 16; k++) {
      float a[4], bb[4];
      for (int i = 0; i < 4; i++) a[i] = As[ty * 4 + i][k];
      for (int j = 0; j < 4; j++) bb[j] = Bs[k][tx * 4 + j];
      for (int i = 0; i < 4; i++)
        for (int j = 0; j < 4; j++) acc[i][j] += a[i] * bb[j];
    }
    __syncthreads();
  }
  for (int i = 0; i < 4; i++)
    for (int j = 0; j < 4; j++) {
      int m = m0 + ty * 4 + i, n = n0 + tx * 4 + j;
      float v = acc[i][j] + b[n];
      g1[(size_t)m * DH + n] = fmaxf(v, 0.f);
    }
}

// logits = g1 @ gw2 + gb2   [8192 x 8], K=512; one wave per token
__global__ __launch_bounds__(256) void k_gate2(const float* __restrict__ g1,
                                               const float* __restrict__ w2,
                                               const float* __restrict__ b2,
                                               float* __restrict__ logits) {
  int wave = threadIdx.x >> 6, lane = threadIdx.x & 63;
  int tok = blockIdx.x * 4 + wave;
  const float* row = &g1[(size_t)tok * DH];
  float v[8];
  for (int j = 0; j < 8; j++) v[j] = row[lane + 64 * j];
  float acc[8];
  for (int e = 0; e < NE; e++) {
    float s = 0.f;
    for (int j = 0; j < 8; j++) s += v[j] * w2[(size_t)(lane + 64 * j) * NE + e];
    acc[e] = s;
  }
  for (int off = 32; off > 0; off >>= 1)
    for (int e = 0; e < NE; e++) acc[e] += __shfl_down(acc[e], off);
  if (lane == 0)
    for (int e = 0; e < NE; e++) logits[(size_t)tok * NE + e] = acc[e] + b2[e];
}

// ---------------- routing ----------------
__global__ __launch_bounds__(256) void k_route(const float* __restrict__ logits,
                                               int* __restrict__ topi,
                                               float* __restrict__ gatesw,
                                               int* __restrict__ counts,
                                               float* __restrict__ psum) {
  int t = blockIdx.x * blockDim.x + threadIdx.x;
  const float* lp = &logits[(size_t)t * NE];
  float l[8];
  for (int e = 0; e < NE; e++) l[e] = lp[e];
  int i0 = 0; float v0 = l[0];
  for (int e = 1; e < NE; e++) if (l[e] > v0) { v0 = l[e]; i0 = e; }
  int i1 = (i0 == 0) ? 1 : 0; float v1 = l[i1];
  for (int e = 0; e < NE; e++)
    if (e != i0 && l[e] > v1) { v1 = l[e]; i1 = e; }
  float g0 = 1.f / (1.f + expf(v1 - v0));
  topi[t * 2] = i0; topi[t * 2 + 1] = i1;
  gatesw[t * 2] = g0; gatesw[t * 2 + 1] = 1.f - g0;
  // full softmax for load-balance loss
  float p[8]; float s = 0.f;
  for (int e = 0; e < NE; e++) { p[e] = expf(l[e] - v0); s += p[e]; }
  float inv = 1.f / s;
  int lane = threadIdx.x & 63;
  for (int e = 0; e < NE; e++) {
    float pe = p[e] * inv;
    for (int off = 32; off > 0; off >>= 1) pe += __shfl_down(pe, off);
    if (lane == 0) atomicAdd(&psum[e], pe);
  }
  for (int e = 0; e < NE; e++) {
    unsigned long long m0 = __ballot(i0 == e);
    unsigned long long m1 = __ballot(i1 == e);
    if (lane == 0) {
      int c = __popcll(m0) + __popcll(m1);
      if (c) atomicAdd(&counts[e], c);
    }
  }
}

__global__ void k_scan(const int* __restrict__ counts, int* __restrict__ offsets,
                       const float* __restrict__ psum, float* __restrict__ loss_out) {
  if (threadIdx.x == 0) {
    int off = 0;
    for (int e = 0; e < NE; e++) { offsets[e] = off; off += counts[e]; }
    offsets[NE] = off;
    float tt = 1.f / NE, loss = 0.f;
    for (int e = 0; e < NE; e++) {
      float pe = psum[e] / (float)T_TOK;
      loss += tt * (logf(tt) - logf(pe + 1e-8f));
    }
    loss_out[0] = loss;
  }
}

__global__ __launch_bounds__(256) void k_fill(const int* __restrict__ topi,
                                              const float* __restrict__ gatesw,
                                              const int* __restrict__ offsets,
                                              int* __restrict__ fill,
                                              int* __restrict__ slot_tok,
                                              float* __restrict__ slot_gate) {
  int t = blockIdx.x * blockDim.x + threadIdx.x;
  for (int k = 0; k < 2; k++) {
    int e = topi[t * 2 + k];
    int pos = offsets[e] + atomicAdd(&fill[e], 1);
    slot_tok[pos] = t;
    slot_gate[pos] = gatesw[t * 2 + k];
  }
}

// ---------------- expert GEMMs (bf16 MFMA, 128x128 tile, BK=32) ----------------
// GEMM1: H[slot, 0..4095] = gelu( xb[token] @ we1[e] + be1[e] ),  K=1024
__global__ __launch_bounds__(256) void k_egemm1(const ushort* __restrict__ xb,
                                                const ushort* __restrict__ w1t,
                                                const float* __restrict__ be1,
                                                const int* __restrict__ slot_tok,
                                                const int* __restrict__ offsets,
                                                ushort* __restrict__ H) {
  int e = blockIdx.z;
  int beg = offsets[e], nrows = offsets[e + 1] - beg;
  int mt = blockIdx.y;
  if (mt * 128 >= nrows) return;
  int n0 = blockIdx.x * 128;
  const ushort* B = w1t + (size_t)e * DFF * DM;

  __shared__ ushort As[128 * 32];
  __shared__ ushort Bs[128 * 32];

  int t = threadIdx.x;
  int wave = t >> 6, lane = t & 63;
  int wr = wave >> 1, wc = wave & 1;

  int r_g0 = mt * 128 + (t >> 2);
  int r_g1 = r_g0 + 64;
  int tok0 = slot_tok[beg + (r_g0 < nrows ? r_g0 : 0)];
  int tok1 = slot_tok[beg + (r_g1 < nrows ? r_g1 : 0)];
  int acol = (t & 3) * 8;
  const ushort* aptr0 = xb + (size_t)tok0 * DM + acol;
  const ushort* aptr1 = xb + (size_t)tok1 * DM + acol;
  const ushort* bptr0 = B + (size_t)(n0 + (t >> 2)) * DM + acol;
  const ushort* bptr1 = B + (size_t)(n0 + (t >> 2) + 64) * DM + acol;
  char* asd = (char*)As + t * 16;
  char* bsd = (char*)Bs + t * 16;

  f32x4 acc[4][4] = {};
  int kq = (lane >> 4) * 8;
  int la = lane & 15;

  for (int k0 = 0; k0 < DM; k0 += 32) {
    gl_lds16(aptr0 + k0, asd);
    gl_lds16(aptr1 + k0, asd + 4096);
    gl_lds16(bptr0 + k0, bsd);
    gl_lds16(bptr1 + k0, bsd + 4096);
    __syncthreads();
    bf16x8 af[4], bfr[4];
    for (int m = 0; m < 4; m++)
      af[m] = *(const bf16x8*)&As[(wr * 64 + m * 16 + la) * 32 + kq];
    for (int n = 0; n < 4; n++)
      bfr[n] = *(const bf16x8*)&Bs[(wc * 64 + n * 16 + la) * 32 + kq];
    for (int m = 0; m < 4; m++)
      for (int n = 0; n < 4; n++)
        acc[m][n] = __builtin_amdgcn_mfma_f32_16x16x32_bf16(af[m], bfr[n], acc[m][n], 0, 0, 0);
    __syncthreads();
  }

  int row0 = mt * 128 + wr * 64;
  int c_of = n0 + wc * 64;
  for (int m = 0; m < 4; m++) {
    int rbase = row0 + m * 16 + ((lane >> 4) << 2);
    for (int n = 0; n < 4; n++) {
      int c = c_of + n * 16 + la;
      float b1 = be1[e * DFF + c];
      f32x4 a = acc[m][n];
      for (int j = 0; j < 4; j++) {
        int rr = rbase + j;
        if (rr < nrows) {
          float v = a[j] + b1;
          float g = 0.5f * v * (1.0f + erff(v * 0.70710678118f));
          H[(size_t)(beg + rr) * DFF + c] = f2bf(g);
        }
      }
    }
  }
}

// GEMM2: y_acc[token] += gate * ((H[slot] @ we2[e] + be2)*escale + ebias),  K=4096
__global__ __launch_bounds__(256) void k_egemm2(const ushort* __restrict__ H,
                                                const ushort* __restrict__ w2t,
                                                const float* __restrict__ be2,
                                                const float* __restrict__ escale,
                                                const float* __restrict__ ebias,
                                                const float* __restrict__ slot_gate,
                                                const int* __restrict__ slot_tok,
                                                const int* __restrict__ offsets,
                                                float* __restrict__ y_acc) {
  int e = blockIdx.z;
  int beg = offsets[e], nrows = offsets[e + 1] - beg;
  int mt = blockIdx.y;
  if (mt * 128 >= nrows) return;
  int n0 = blockIdx.x * 128;
  const ushort* B = w2t + (size_t)e * DM * DFF;

  __shared__ ushort As[128 * 32];
  __shared__ ushort Bs[128 * 32];

  int t = threadIdx.x;
  int wave = t >> 6, lane = t & 63;
  int wr = wave >> 1, wc = wave & 1;

  int r_g0 = mt * 128 + (t >> 2);
  int r_g1 = r_g0 + 64;
  int s0 = beg + (r_g0 < nrows ? r_g0 : 0);
  int s1 = beg + (r_g1 < nrows ? r_g1 : 0);
  int acol = (t & 3) * 8;
  const ushort* aptr0 = H + (size_t)s0 * DFF + acol;
  const ushort* aptr1 = H + (size_t)s1 * DFF + acol;
  const ushort* bptr0 = B + (size_t)(n0 + (t >> 2)) * DFF + acol;
  const ushort* bptr1 = B + (size_t)(n0 + (t >> 2) + 64) * DFF + acol;
  char* asd = (char*)As + t * 16;
  char* bsd = (char*)Bs + t * 16;

  f32x4 acc[4][4] = {};
  int kq = (lane >> 4) * 8;
  int la = lane & 15;

  for (int k0 = 0; k0 < DFF; k0 += 32) {
    gl_lds16(aptr0 + k0, asd);
    gl_lds16(aptr1 + k0, asd + 4096);
    gl_lds16(bptr0 + k0, bsd);
    gl_lds16(bptr1 + k0, bsd + 4096);
    __syncthreads();
    bf16x8 af[4], bfr[4];
    for (int m = 0; m < 4; m++)
      af[m] = *(const bf16x8*)&As[(wr * 64 + m * 16 + la) * 32 + kq];
    for (int n = 0; n < 4; n++)
      bfr[n] = *(const bf16x8*)&Bs[(wc * 64 + n * 16 + la) * 32 + kq];
    for (int m = 0; m < 4; m++)
      for (int n = 0; n < 4; n++)
        acc[m][n] = __builtin_amdgcn_mfma_f32_16x16x32_bf16(af[m], bfr[n], acc[m][n], 0, 0, 0);
    __syncthreads();
  }

  int row0 = mt * 128 + wr * 64;
  int c_of = n0 + wc * 64;
  for (int m = 0; m < 4; m++) {
    int rbase = row0 + m * 16 + ((lane >> 4) << 2);
    for (int n = 0; n < 4; n++) {
      int c = c_of + n * 16 + la;
      float b2 = be2[e * DM + c];
      float sc = escale[e * DM + c];
      float bb = ebias[e * DM + c];
      f32x4 a = acc[m][n];
      for (int j = 0; j < 4; j++) {
        int rr = rbase + j;
        if (rr < nrows) {
          int s = beg + rr;
          float v = (a[j] + b2) * sc + bb;
          atomicAdd(&y_acc[(size_t)slot_tok[s] * DM + c], slot_gate[s] * v);
        }
      }
    }
  }
}

// ---------------- residual + LayerNorm ----------------
__global__ __launch_bounds__(256) void k_ln(const float* __restrict__ x,
                                            const float* __restrict__ y_acc,
                                            const float* __restrict__ gamma,
                                            const float* __restrict__ beta,
                                            float* __restrict__ y) {
  int t = blockIdx.x;
  const float* xr = &x[(size_t)t * DM];
  const float* ar = &y_acc[(size_t)t * DM];
  int tid = threadIdx.x;
  float v[4];
  float sum = 0.f;
  for (int i = 0; i < 4; i++) {
    int c = tid + i * 256;
    v[i] = xr[c] + ar[c];
    sum += v[i];
  }
  __shared__ float red[4];
  __shared__ float red2[4];
  for (int off = 32; off > 0; off >>= 1) sum += __shfl_down(sum, off);
  if ((tid & 63) == 0) red[tid >> 6] = sum;
  __syncthreads();
  float mu = (red[0] + red[1] + red[2] + red[3]) * (1.f / DM);
  float vs = 0.f;
  for (int i = 0; i < 4; i++) { float d = v[i] - mu; vs += d * d; }
  for (int off = 32; off > 0; off >>= 1) vs += __shfl_down(vs, off);
  if ((tid & 63) == 0) red2[tid >> 6] = vs;
  __syncthreads();
  float var = (red2[0] + red2[1] + red2[2] + red2[3]) * (1.f / DM);
  float rs = rsqrtf(var + 1e-5f);
  for (int i = 0; i < 4; i++) {
    int c = tid + i * 256;
    y[(size_t)t * DM + c] = (v[i] - mu) * rs * gamma[c] + beta[c];
  }
}

extern "C" void kernel_launch(void* const* d_in, const int* in_sizes, int n_in,
                              void* d_out, int out_size, void* d_ws, size_t ws_size,
                              hipStream_t stream) {
  const float* x    = (const float*)d_in[0];
  const float* gw1  = (const float*)d_in[1];
  const float* gb1  = (const float*)d_in[2];
  const float* gw2  = (const float*)d_in[3];
  const float* gb2  = (const float*)d_in[4];
  const float* we1  = (const float*)d_in[5];
  const float* be1  = (const float*)d_in[6];
  const float* we2  = (const float*)d_in[7];
  const float* be2  = (const float*)d_in[8];
  const float* escale = (const float*)d_in[9];
  const float* ebias  = (const float*)d_in[10];
  const float* gamma  = (const float*)d_in[11];
  const float* beta   = (const float*)d_in[12];
  float* y = (float*)d_out;
  float* loss_out = y + (size_t)T_TOK * DM;

  char* w = (char*)d_ws;
  ushort* xb    = (ushort*)w; w += (size_t)T_TOK * DM * 2;
  ushort* w1t   = (ushort*)w; w += (size_t)NE * DFF * DM * 2;
  ushort* w2t   = (ushort*)w; w += (size_t)NE * DM * DFF * 2;
  ushort* H     = (ushort*)w; w += (size_t)NSLOT * DFF * 2;
  float* y_acc  = (float*)w;  w += (size_t)T_TOK * DM * 4;
  float* g1     = (float*)w;  w += (size_t)T_TOK * DH * 4;
  float* logits = (float*)w;  w += (size_t)T_TOK * NE * 4;
  int*   topi   = (int*)w;    w += (size_t)T_TOK * 2 * 4;
  float* gatesw = (float*)w;  w += (size_t)T_TOK * 2 * 4;
  int* slot_tok = (int*)w;    w += (size_t)NSLOT * 4;
  float* slot_gate = (float*)w; w += (size_t)NSLOT * 4;
  int* counts   = (int*)w;    w += 64;
  int* fill     = (int*)w;    w += 64;
  int* offsets  = (int*)w;    w += 64;
  float* psum   = (float*)w;  w += 64;

  k_init<<<1, 64, 0, stream>>>(counts, fill, psum);
  k_zero4<<<2048, 256, 0, stream>>>(y_acc, T_TOK * DM / 4);
  k_cvt_x<<<2048, 256, 0, stream>>>(x, xb, T_TOK * DM / 4);
  k_tr<<<dim3(64, 16, 8), 256, 0, stream>>>(we1, w1t, DM, DFF);
  k_tr<<<dim3(16, 64, 8), 256, 0, stream>>>(we2, w2t, DFF, DM);
  k_gate1<<<dim3(DH / 64, T_TOK / 64), 256, 0, stream>>>(x, gw1, gb1, g1);
  k_gate2<<<T_TOK / 4, 256, 0, stream>>>(g1, gw2, gb2, logits);
  k_route<<<T_TOK / 256, 256, 0, stream>>>(logits, topi, gatesw, counts, psum);
  k_scan<<<1, 64, 0, stream>>>(counts, offsets, psum, loss_out);
  k_fill<<<T_TOK / 256, 256, 0, stream>>>(topi, gatesw, offsets, fill, slot_tok, slot_gate);
  k_egemm1<<<dim3(DFF / 128, NSLOT / 128 / 2, NE), 256, 0, stream>>>(xb, w1t, be1, slot_tok, offsets, H);
  k_egemm2<<<dim3(DM / 128, NSLOT / 128 / 2, NE), 256, 0, stream>>>(H, w2t, be2, escale, ebias,
                                                                    slot_gate, slot_tok, offsets, y_acc);
  k_ln<<<T_TOK, 256, 0, stream>>>(x, y_acc, gamma, beta, y);
}

// Round 2
// 927.796 us; speedup vs baseline: 3.3590x; 3.3590x over previous
//
#include <hip/hip_runtime.h>
#include <hip/hip_bf16.h>
#include <math.h>

#define T_TOK 8192
#define DM    1024
#define DFF   4096
#define NE    8
#define DH    512
#define NSLOT (T_TOK*2)

typedef float  f32x4  __attribute__((ext_vector_type(4)));
typedef __bf16 bf16x8 __attribute__((ext_vector_type(8)));

__device__ inline ushort f2bf(float f) {
  union { float f; unsigned int u; } v; v.f = f;
  unsigned int r = (v.u + 0x7FFFu + ((v.u >> 16) & 1u)) >> 16;
  return (ushort)r;
}

// branch-free erf-based GELU (A&S 7.1.26, max abs err ~1.5e-7)
__device__ __forceinline__ float gelu_erf(float v) {
  float xx = v * 0.70710678118654752f;
  float ax = fabsf(xx);
  float t  = __builtin_amdgcn_rcpf(1.f + 0.3275911f * ax);
  float p  = t * (0.254829592f + t * (-0.284496736f + t * (1.421413741f +
             t * (-1.453152027f + t * 1.061405429f))));
  float er = 1.f - p * __expf(-ax * ax);
  er = copysignf(er, xx);
  return 0.5f * v * (1.f + er);
}

__device__ inline void gl_lds16(const void* g, void* l) {
  __builtin_amdgcn_global_load_lds(
      (const __attribute__((address_space(1))) unsigned int*)g,
      (__attribute__((address_space(3))) unsigned int*)l, 16, 0, 0);
}

// ---------------- init / utility ----------------
__global__ void k_init(int* counts, int* fill, float* psum) {
  int i = threadIdx.x;
  if (i < NE) { counts[i] = 0; fill[i] = 0; psum[i] = 0.f; }
}

__global__ void k_zero4(float* p, int n4) {
  int i = blockIdx.x * blockDim.x + threadIdx.x;
  int st = gridDim.x * blockDim.x;
  float4 z = make_float4(0.f, 0.f, 0.f, 0.f);
  for (; i < n4; i += st) ((float4*)p)[i] = z;
}

__global__ void k_cvt_x(const float* __restrict__ x, ushort* __restrict__ xb, int n4) {
  int i = blockIdx.x * blockDim.x + threadIdx.x;
  int st = gridDim.x * blockDim.x;
  for (; i < n4; i += st) {
    float4 v = ((const float4*)x)[i];
    ushort4 o;
    o.x = f2bf(v.x); o.y = f2bf(v.y); o.z = f2bf(v.z); o.w = f2bf(v.w);
    ((ushort4*)xb)[i] = o;
  }
}

// transpose f32 [R][C] -> bf16 [C][R], one expert per blockIdx.z
__global__ __launch_bounds__(256) void k_tr(const float* __restrict__ in,
                                            ushort* __restrict__ out, int R, int C) {
  __shared__ float tile[64][65];
  int e = blockIdx.z;
  in  += (size_t)e * R * C;
  out += (size_t)e * R * C;
  int r0 = blockIdx.y * 64, c0 = blockIdx.x * 64;
  int tx = threadIdx.x & 63, ty = threadIdx.x >> 6;
  for (int i = 0; i < 16; i++) {
    int r = ty + i * 4;
    tile[r][tx] = in[(size_t)(r0 + r) * C + c0 + tx];
  }
  __syncthreads();
  for (int i = 0; i < 16; i++) {
    int c = ty + i * 4;
    out[(size_t)(c0 + c) * R + r0 + tx] = f2bf(tile[tx][c]);
  }
}

// ---------------- gating (fp32) ----------------
// g1 = relu(x @ gw1 + gb1)   [8192 x 512], K=1024
__global__ __launch_bounds__(256) void k_gate1(const float* __restrict__ x,
                                               const float* __restrict__ w,
                                               const float* __restrict__ b,
                                               float* __restrict__ g1) {
  __shared__ float As[64][17];
  __shared__ float Bs[16][65];
  int m0 = blockIdx.y * 64, n0 = blockIdx.x * 64;
  int t = threadIdx.x;
  int tx = t & 15, ty = t >> 4;
  float acc[4][4] = {};
  for (int k0 = 0; k0 < DM; k0 += 16) {
    {
      int r = t >> 2, c4 = (t & 3) * 4;
      float4 v = *(const float4*)&x[(size_t)(m0 + r) * DM + k0 + c4];
      As[r][c4 + 0] = v.x; As[r][c4 + 1] = v.y; As[r][c4 + 2] = v.z; As[r][c4 + 3] = v.w;
    }
    {
      int r = t >> 4, c4 = (t & 15) * 4;
      float4 v = *(const float4*)&w[(size_t)(k0 + r) * DH + n0 + c4];
      Bs[r][c4 + 0] = v.x; Bs[r][c4 + 1] = v.y; Bs[r][c4 + 2] = v.z; Bs[r][c4 + 3] = v.w;
    }
    __syncthreads();
#pragma unroll
    for (int k = 0; k < 16; k++) {
      float a[4], bb[4];
#pragma unroll
      for (int i = 0; i < 4; i++) a[i] = As[ty * 4 + i][k];
#pragma unroll
      for (int j = 0; j < 4; j++) bb[j] = Bs[k][tx * 4 + j];
#pragma unroll
      for (int i = 0; i < 4; i++)
#pragma unroll
        for (int j = 0; j < 4; j++) acc[i][j] += a[i] * bb[j];
    }
    __syncthreads();
  }
#pragma unroll
  for (int i = 0; i < 4; i++)
#pragma unroll
    for (int j = 0; j < 4; j++) {
      int m = m0 + ty * 4 + i, n = n0 + tx * 4 + j;
      float v = acc[i][j] + b[n];
      g1[(size_t)m * DH + n] = fmaxf(v, 0.f);
    }
}

// logits = g1 @ gw2 + gb2   [8192 x 8], K=512; one wave per token
__global__ __launch_bounds__(256) void k_gate2(const float* __restrict__ g1,
                                               const float* __restrict__ w2,
                                               const float* __restrict__ b2,
                                               float* __restrict__ logits) {
  int wave = threadIdx.x >> 6, lane = threadIdx.x & 63;
  int tok = blockIdx.x * 4 + wave;
  const float* row = &g1[(size_t)tok * DH];
  float v[8];
#pragma unroll
  for (int j = 0; j < 8; j++) v[j] = row[lane + 64 * j];
  float acc[8];
#pragma unroll
  for (int e = 0; e < NE; e++) {
    float s = 0.f;
#pragma unroll
    for (int j = 0; j < 8; j++) s += v[j] * w2[(size_t)(lane + 64 * j) * NE + e];
    acc[e] = s;
  }
  for (int off = 32; off > 0; off >>= 1)
#pragma unroll
    for (int e = 0; e < NE; e++) acc[e] += __shfl_down(acc[e], off);
  if (lane == 0)
#pragma unroll
    for (int e = 0; e < NE; e++) logits[(size_t)tok * NE + e] = acc[e] + b2[e];
}

// ---------------- routing ----------------
__global__ __launch_bounds__(256) void k_route(const float* __restrict__ logits,
                                               int* __restrict__ topi,
                                               float* __restrict__ gatesw,
                                               int* __restrict__ counts,
                                               float* __restrict__ psum) {
  int t = blockIdx.x * blockDim.x + threadIdx.x;
  const float* lp = &logits[(size_t)t * NE];
  float l[8];
#pragma unroll
  for (int e = 0; e < NE; e++) l[e] = lp[e];
  int i0 = 0; float v0 = l[0];
#pragma unroll
  for (int e = 1; e < NE; e++) if (l[e] > v0) { v0 = l[e]; i0 = e; }
  int i1 = (i0 == 0) ? 1 : 0; float v1 = l[i1];
#pragma unroll
  for (int e = 0; e < NE; e++)
    if (e != i0 && l[e] > v1) { v1 = l[e]; i1 = e; }
  float g0 = 1.f / (1.f + expf(v1 - v0));
  topi[t * 2] = i0; topi[t * 2 + 1] = i1;
  gatesw[t * 2] = g0; gatesw[t * 2 + 1] = 1.f - g0;
  // full softmax for load-balance loss
  float p[8]; float s = 0.f;
#pragma unroll
  for (int e = 0; e < NE; e++) { p[e] = expf(l[e] - v0); s += p[e]; }
  float inv = 1.f / s;
  int lane = threadIdx.x & 63;
#pragma unroll
  for (int e = 0; e < NE; e++) {
    float pe = p[e] * inv;
    for (int off = 32; off > 0; off >>= 1) pe += __shfl_down(pe, off);
    if (lane == 0) atomicAdd(&psum[e], pe);
  }
#pragma unroll
  for (int e = 0; e < NE; e++) {
    unsigned long long m0 = __ballot(i0 == e);
    unsigned long long m1 = __ballot(i1 == e);
    if (lane == 0) {
      int c = __popcll(m0) + __popcll(m1);
      if (c) atomicAdd(&counts[e], c);
    }
  }
}

__global__ void k_scan(const int* __restrict__ counts, int* __restrict__ offsets,
                       const float* __restrict__ psum, float* __restrict__ loss_out) {
  if (threadIdx.x == 0) {
    int off = 0;
    for (int e = 0; e < NE; e++) { offsets[e] = off; off += counts[e]; }
    offsets[NE] = off;
    float tt = 1.f / NE, loss = 0.f;
    for (int e = 0; e < NE; e++) {
      float pe = psum[e] / (float)T_TOK;
      loss += tt * (logf(tt) - logf(pe + 1e-8f));
    }
    loss_out[0] = loss;
  }
}

__global__ __launch_bounds__(256) void k_fill(const int* __restrict__ topi,
                                              const float* __restrict__ gatesw,
                                              const int* __restrict__ offsets,
                                              int* __restrict__ fill,
                                              int* __restrict__ slot_tok,
                                              float* __restrict__ slot_gate) {
  int t = blockIdx.x * blockDim.x + threadIdx.x;
  for (int k = 0; k < 2; k++) {
    int e = topi[t * 2 + k];
    int pos = offsets[e] + atomicAdd(&fill[e], 1);
    slot_tok[pos] = t;
    slot_gate[pos] = gatesw[t * 2 + k];
  }
}

// ---------------- expert GEMMs (bf16 MFMA, 128x128 tile, BK=32) ----------------
// GEMM1: H[slot, 0..4095] = gelu( xb[token] @ we1[e] + be1[e] ),  K=1024
__global__ __launch_bounds__(256) void k_egemm1(const ushort* __restrict__ xb,
                                                const ushort* __restrict__ w1t,
                                                const float* __restrict__ be1,
                                                const int* __restrict__ slot_tok,
                                                const int* __restrict__ offsets,
                                                ushort* __restrict__ H) {
  int e = blockIdx.z;
  int beg = offsets[e], nrows = offsets[e + 1] - beg;
  int mt = blockIdx.y;
  if (mt * 128 >= nrows) return;
  int n0 = blockIdx.x * 128;
  const ushort* B = w1t + (size_t)e * DFF * DM;

  __shared__ ushort As[128 * 32];
  __shared__ ushort Bs[128 * 32];

  int t = threadIdx.x;
  int wave = t >> 6, lane = t & 63;
  int wr = wave >> 1, wc = wave & 1;

  int r_g0 = mt * 128 + (t >> 2);
  int r_g1 = r_g0 + 64;
  int tok0 = slot_tok[beg + (r_g0 < nrows ? r_g0 : 0)];
  int tok1 = slot_tok[beg + (r_g1 < nrows ? r_g1 : 0)];
  int acol = (t & 3) * 8;
  const ushort* aptr0 = xb + (size_t)tok0 * DM + acol;
  const ushort* aptr1 = xb + (size_t)tok1 * DM + acol;
  const ushort* bptr0 = B + (size_t)(n0 + (t >> 2)) * DM + acol;
  const ushort* bptr1 = B + (size_t)(n0 + (t >> 2) + 64) * DM + acol;
  char* asd = (char*)As + t * 16;
  char* bsd = (char*)Bs + t * 16;

  f32x4 acc[4][4] = {};
  int kq = (lane >> 4) * 8;
  int la = lane & 15;

  for (int k0 = 0; k0 < DM; k0 += 32) {
    gl_lds16(aptr0 + k0, asd);
    gl_lds16(aptr1 + k0, asd + 4096);
    gl_lds16(bptr0 + k0, bsd);
    gl_lds16(bptr1 + k0, bsd + 4096);
    __syncthreads();
    bf16x8 af[4], bfr[4];
#pragma unroll
    for (int m = 0; m < 4; m++)
      af[m] = *(const bf16x8*)&As[(wr * 64 + m * 16 + la) * 32 + kq];
#pragma unroll
    for (int n = 0; n < 4; n++)
      bfr[n] = *(const bf16x8*)&Bs[(wc * 64 + n * 16 + la) * 32 + kq];
#pragma unroll
    for (int m = 0; m < 4; m++)
#pragma unroll
      for (int n = 0; n < 4; n++)
        acc[m][n] = __builtin_amdgcn_mfma_f32_16x16x32_bf16(af[m], bfr[n], acc[m][n], 0, 0, 0);
    __syncthreads();
  }

  int row0 = mt * 128 + wr * 64;
  int c_of = n0 + wc * 64;
#pragma unroll
  for (int m = 0; m < 4; m++) {
    int rbase = row0 + m * 16 + ((lane >> 4) << 2);
#pragma unroll
    for (int n = 0; n < 4; n++) {
      int c = c_of + n * 16 + la;
      float b1 = be1[e * DFF + c];
      f32x4 a = acc[m][n];
#pragma unroll
      for (int j = 0; j < 4; j++) {
        int rr = rbase + j;
        if (rr < nrows) {
          float v = a[j] + b1;
          H[(size_t)(beg + rr) * DFF + c] = f2bf(gelu_erf(v));
        }
      }
    }
  }
}

// GEMM2: y_acc[token] += gate * ((H[slot] @ we2[e] + be2)*escale + ebias),  K=4096
__global__ __launch_bounds__(256) void k_egemm2(const ushort* __restrict__ H,
                                                const ushort* __restrict__ w2t,
                                                const float* __restrict__ be2,
                                                const float* __restrict__ escale,
                                                const float* __restrict__ ebias,
                                                const float* __restrict__ slot_gate,
                                                const int* __restrict__ slot_tok,
                                                const int* __restrict__ offsets,
                                                float* __restrict__ y_acc) {
  int e = blockIdx.z;
  int beg = offsets[e], nrows = offsets[e + 1] - beg;
  int mt = blockIdx.y;
  if (mt * 128 >= nrows) return;
  int n0 = blockIdx.x * 128;
  const ushort* B = w2t + (size_t)e * DM * DFF;

  __shared__ ushort As[128 * 32];
  __shared__ ushort Bs[128 * 32];

  int t = threadIdx.x;
  int wave = t >> 6, lane = t & 63;
  int wr = wave >> 1, wc = wave & 1;

  int r_g0 = mt * 128 + (t >> 2);
  int r_g1 = r_g0 + 64;
  int s0 = beg + (r_g0 < nrows ? r_g0 : 0);
  int s1 = beg + (r_g1 < nrows ? r_g1 : 0);
  int acol = (t & 3) * 8;
  const ushort* aptr0 = H + (size_t)s0 * DFF + acol;
  const ushort* aptr1 = H + (size_t)s1 * DFF + acol;
  const ushort* bptr0 = B + (size_t)(n0 + (t >> 2)) * DFF + acol;
  const ushort* bptr1 = B + (size_t)(n0 + (t >> 2) + 64) * DFF + acol;
  char* asd = (char*)As + t * 16;
  char* bsd = (char*)Bs + t * 16;

  f32x4 acc[4][4] = {};
  int kq = (lane >> 4) * 8;
  int la = lane & 15;

  for (int k0 = 0; k0 < DFF; k0 += 32) {
    gl_lds16(aptr0 + k0, asd);
    gl_lds16(aptr1 + k0, asd + 4096);
    gl_lds16(bptr0 + k0, bsd);
    gl_lds16(bptr1 + k0, bsd + 4096);
    __syncthreads();
    bf16x8 af[4], bfr[4];
#pragma unroll
    for (int m = 0; m < 4; m++)
      af[m] = *(const bf16x8*)&As[(wr * 64 + m * 16 + la) * 32 + kq];
#pragma unroll
    for (int n = 0; n < 4; n++)
      bfr[n] = *(const bf16x8*)&Bs[(wc * 64 + n * 16 + la) * 32 + kq];
#pragma unroll
    for (int m = 0; m < 4; m++)
#pragma unroll
      for (int n = 0; n < 4; n++)
        acc[m][n] = __builtin_amdgcn_mfma_f32_16x16x32_bf16(af[m], bfr[n], acc[m][n], 0, 0, 0);
    __syncthreads();
  }

  int row0 = mt * 128 + wr * 64;
  int c_of = n0 + wc * 64;
#pragma unroll
  for (int m = 0; m < 4; m++) {
    int rbase = row0 + m * 16 + ((lane >> 4) << 2);
#pragma unroll
    for (int n = 0; n < 4; n++) {
      int c = c_of + n * 16 + la;
      float b2 = be2[e * DM + c];
      float sc = escale[e * DM + c];
      float bb = ebias[e * DM + c];
      f32x4 a = acc[m][n];
#pragma unroll
      for (int j = 0; j < 4; j++) {
        int rr = rbase + j;
        if (rr < nrows) {
          int s = beg + rr;
          float v = (a[j] + b2) * sc + bb;
          atomicAdd(&y_acc[(size_t)slot_tok[s] * DM + c], slot_gate[s] * v);
        }
      }
    }
  }
}

// ---------------- residual + LayerNorm ----------------
__global__ __launch_bounds__(256) void k_ln(const float* __restrict__ x,
                                            const float* __restrict__ y_acc,
                                            const float* __restrict__ gamma,
                                            const float* __restrict__ beta,
                                            float* __restrict__ y) {
  int t = blockIdx.x;
  const float* xr = &x[(size_t)t * DM];
  const float* ar = &y_acc[(size_t)t * DM];
  int tid = threadIdx.x;
  float v[4];
  float sum = 0.f;
#pragma unroll
  for (int i = 0; i < 4; i++) {
    int c = tid + i * 256;
    v[i] = xr[c] + ar[c];
    sum += v[i];
  }
  __shared__ float red[4];
  __shared__ float red2[4];
  for (int off = 32; off > 0; off >>= 1) sum += __shfl_down(sum, off);
  if ((tid & 63) == 0) red[tid >> 6] = sum;
  __syncthreads();
  float mu = (red[0] + red[1] + red[2] + red[3]) * (1.f / DM);
  float vs = 0.f;
#pragma unroll
  for (int i = 0; i < 4; i++) { float d = v[i] - mu; vs += d * d; }
  for (int off = 32; off > 0; off >>= 1) vs += __shfl_down(vs, off);
  if ((tid & 63) == 0) red2[tid >> 6] = vs;
  __syncthreads();
  float var = (red2[0] + red2[1] + red2[2] + red2[3]) * (1.f / DM);
  float rs = rsqrtf(var + 1e-5f);
#pragma unroll
  for (int i = 0; i < 4; i++) {
    int c = tid + i * 256;
    y[(size_t)t * DM + c] = (v[i] - mu) * rs * gamma[c] + beta[c];
  }
}

extern "C" void kernel_launch(void* const* d_in, const int* in_sizes, int n_in,
                              void* d_out, int out_size, void* d_ws, size_t ws_size,
                              hipStream_t stream) {
  const float* x    = (const float*)d_in[0];
  const float* gw1  = (const float*)d_in[1];
  const float* gb1  = (const float*)d_in[2];
  const float* gw2  = (const float*)d_in[3];
  const float* gb2  = (const float*)d_in[4];
  const float* we1  = (const float*)d_in[5];
  const float* be1  = (const float*)d_in[6];
  const float* we2  = (const float*)d_in[7];
  const float* be2  = (const float*)d_in[8];
  const float* escale = (const float*)d_in[9];
  const float* ebias  = (const float*)d_in[10];
  const float* gamma  = (const float*)d_in[11];
  const float* beta   = (const float*)d_in[12];
  float* y = (float*)d_out;
  float* loss_out = y + (size_t)T_TOK * DM;

  char* w = (char*)d_ws;
  ushort* xb    = (ushort*)w; w += (size_t)T_TOK * DM * 2;
  ushort* w1t   = (ushort*)w; w += (size_t)NE * DFF * DM * 2;
  ushort* w2t   = (ushort*)w; w += (size_t)NE * DM * DFF * 2;
  ushort* H     = (ushort*)w; w += (size_t)NSLOT * DFF * 2;
  float* y_acc  = (float*)w;  w += (size_t)T_TOK * DM * 4;
  float* g1     = (float*)w;  w += (size_t)T_TOK * DH * 4;
  float* logits = (float*)w;  w += (size_t)T_TOK * NE * 4;
  int*   topi   = (int*)w;    w += (size_t)T_TOK * 2 * 4;
  float* gatesw = (float*)w;  w += (size_t)T_TOK * 2 * 4;
  int* slot_tok = (int*)w;    w += (size_t)NSLOT * 4;
  float* slot_gate = (float*)w; w += (size_t)NSLOT * 4;
  int* counts   = (int*)w;    w += 64;
  int* fill     = (int*)w;    w += 64;
  int* offsets  = (int*)w;    w += 64;
  float* psum   = (float*)w;  w += 64;

  k_init<<<1, 64, 0, stream>>>(counts, fill, psum);
  k_zero4<<<2048, 256, 0, stream>>>(y_acc, T_TOK * DM / 4);
  k_cvt_x<<<2048, 256, 0, stream>>>(x, xb, T_TOK * DM / 4);
  k_tr<<<dim3(64, 16, 8), 256, 0, stream>>>(we1, w1t, DM, DFF);
  k_tr<<<dim3(16, 64, 8), 256, 0, stream>>>(we2, w2t, DFF, DM);
  k_gate1<<<dim3(DH / 64, T_TOK / 64), 256, 0, stream>>>(x, gw1, gb1, g1);
  k_gate2<<<T_TOK / 4, 256, 0, stream>>>(g1, gw2, gb2, logits);
  k_route<<<T_TOK / 256, 256, 0, stream>>>(logits, topi, gatesw, counts, psum);
  k_scan<<<1, 64, 0, stream>>>(counts, offsets, psum, loss_out);
  k_fill<<<T_TOK / 256, 256, 0, stream>>>(topi, gatesw, offsets, fill, slot_tok, slot_gate);
  k_egemm1<<<dim3(DFF / 128, NSLOT / 128 / 2, NE), 256, 0, stream>>>(xb, w1t, be1, slot_tok, offsets, H);
  k_egemm2<<<dim3(DM / 128, NSLOT / 128 / 2, NE), 256, 0, stream>>>(H, w2t, be2, escale, ebias,
                                                                    slot_gate, slot_tok, offsets, y_acc);
  k_ln<<<T_TOK, 256, 0, stream>>>(x, y_acc, gamma, beta, y);
}